// Round 13
// baseline (111.699 us; speedup 1.0000x reference)
//
#include <hip/hip_runtime.h>
#include <cstdint>
#include <cstddef>

#define NN 8192
#define INF 512
#define OUTF 64
#define ALPHA 0.2f
#define NSPLIT 2
#define JSPLIT (NN / NSPLIT)   // 4096
#define NSS (JSPLIT / 128)     // 32 supersteps per block

typedef short bf16x8 __attribute__((ext_vector_type(8)));
typedef float f32x4 __attribute__((ext_vector_type(4)));

static __device__ inline unsigned short f2bf(float f) {
    unsigned u = __builtin_bit_cast(unsigned, f);
    unsigned r = (u + 0x7FFFu + ((u >> 16) & 1u)) >> 16;
    return (unsigned short)r;
}

// ---------------------------------------------------------------------------
// Kernel 1: Wh = x @ W (proven path, verbatim from round 12). Writes Asw
// (MFMA-A-swizzled bf16 Wh), U = exp(0.8 s1), E2p = exp(s2), E2n = exp(0.2 s2).
// ---------------------------------------------------------------------------
__global__ __launch_bounds__(256) void k1_gemm(
    const float* __restrict__ x, const float* __restrict__ W,
    const float* __restrict__ a, unsigned short* __restrict__ Asw,
    float* __restrict__ U, float* __restrict__ E2p, float* __restrict__ E2n)
{
    const int tid = threadIdx.x;
    const int i0  = blockIdx.x * 16;
    const int w   = __builtin_amdgcn_readfirstlane(tid >> 6);
    const int c   = tid & 63;

    const float* xr = x + (size_t)(i0 + 4 * w) * INF;
    const float* Wc = W + c;
    float acc[4] = {0.f, 0.f, 0.f, 0.f};

    #pragma unroll 4
    for (int kk = 0; kk < 128; ++kk) {
        const float4 x0 = *(const float4*)(xr + 0 * INF + kk * 4);
        const float4 x1 = *(const float4*)(xr + 1 * INF + kk * 4);
        const float4 x2 = *(const float4*)(xr + 2 * INF + kk * 4);
        const float4 x3 = *(const float4*)(xr + 3 * INF + kk * 4);
        const float w0 = Wc[(kk * 4 + 0) * OUTF];
        const float w1 = Wc[(kk * 4 + 1) * OUTF];
        const float w2 = Wc[(kk * 4 + 2) * OUTF];
        const float w3 = Wc[(kk * 4 + 3) * OUTF];
        acc[0] = fmaf(x0.x, w0, fmaf(x0.y, w1, fmaf(x0.z, w2, fmaf(x0.w, w3, acc[0]))));
        acc[1] = fmaf(x1.x, w0, fmaf(x1.y, w1, fmaf(x1.z, w2, fmaf(x1.w, w3, acc[1]))));
        acc[2] = fmaf(x2.x, w0, fmaf(x2.y, w1, fmaf(x2.z, w2, fmaf(x2.w, w3, acc[2]))));
        acc[3] = fmaf(x3.x, w0, fmaf(x3.y, w1, fmaf(x3.z, w2, fmaf(x3.w, w3, acc[3]))));
    }

    const float a1c = a[c];
    const float a2c = a[64 + c];
    #pragma unroll
    for (int q = 0; q < 4; ++q) {
        float v1 = acc[q] * a1c;
        float v2 = acc[q] * a2c;
        #pragma unroll
        for (int m = 32; m; m >>= 1) {
            v1 += __shfl_xor(v1, m, 64);
            v2 += __shfl_xor(v2, m, 64);
        }
        if (c == 0) {
            const int i = i0 + 4 * w + q;
            U[i]   = __expf((1.0f - ALPHA) * v1);
            E2p[i] = __expf(v2);
            E2n[i] = __expf(ALPHA * v2);
        }
    }

    const int i   = i0 + 4 * w;
    const int jt  = i >> 5;
    const int sub = (i >> 3) & 3;
    const int e0  = i & 7;
    ushort4 pk;
    pk.x = f2bf(acc[0]); pk.y = f2bf(acc[1]);
    pk.z = f2bf(acc[2]); pk.w = f2bf(acc[3]);
    *(ushort4*)&Asw[((size_t)(c >> 4) * 256 + jt) * 512 + ((c & 15) + 16 * sub) * 8 + e0] = pk;
}

// ---------------------------------------------------------------------------
// Kernel 2 (fused, raw-barrier pipelined): one pass over adj computing the
// attention in-flight. Block = 16 rows x 4096-col split; 32 supersteps of
// 128 cols. Reg-staged double-buffer (T14): global loads for ss+2 stay in
// flight across RAW s_barriers (no vmcnt(0) drain); compiler's dataflow
// vmcnt waits handle all reg hazards; manual lgkmcnt(0) flushes ds_writes
// before each barrier. No bitmask intermediate.
// ---------------------------------------------------------------------------
__global__ __launch_bounds__(256) void k2_fused(
    const int* __restrict__ adj, const unsigned short* __restrict__ Asw,
    const float* __restrict__ Ug, const float* __restrict__ E2pg,
    const float* __restrict__ E2ng,
    float* __restrict__ Opart, float* __restrict__ lpart)
{
    __shared__ int   bufS[2][2048];   // 2 x 8 KB staging (reused as red)
    __shared__ float redl[64];

    const int tid   = threadIdx.x;
    const int l     = tid & 63;
    const int w     = tid >> 6;
    const int split = blockIdx.x & 1;
    const int i0    = (int)(blockIdx.x >> 1) * 16;
    const int jbase = split * JSPLIT;

    const int il  = l & 15;
    const int kg8 = (l >> 4) * 8;
    const float ua = Ug[i0 + il];

    f32x4 a0 = {0,0,0,0}, a1 = {0,0,0,0}, a2 = {0,0,0,0}, a3 = {0,0,0,0};
    float rs = 0.f;

    // staging addresses: wave w covers rows 4w..4w+3; 2 int4 chunks per lane
    const int grow = i0 + 4 * w + (l >> 5);
    const int* gs0 = adj + (size_t)grow * NN + jbase + (l & 31) * 4;
    const int* gs1 = gs0 + (size_t)2 * NN;
    int* lw0 = &bufS[0][w * 512 + l * 4];
    int* lw1 = &bufS[1][w * 512 + l * 4];

    int4 rA0, rA1, rB0, rB1;
    // prologue: stage0 -> rA -> buf0;  stage1 -> rB (in flight)
    rA0 = *(const int4*)(gs0);
    rA1 = *(const int4*)(gs1);
    rB0 = *(const int4*)(gs0 + 128);
    rB1 = *(const int4*)(gs1 + 128);
    *(int4*)(lw0)       = rA0;    // compiler emits counted vmcnt for rA here
    *(int4*)(lw0 + 256) = rA1;

#define SCM(EP, EN, M) ((M) ? fmaxf(ua * (EP), (EN)) : 0.f)

#define STEP(SS, RN0, RN1, RW0, RW1, LWN)  do {                               \
    /* issue stage SS+2 loads (stay in flight across both barriers) */        \
    if ((SS) + 2 < NSS) {                                                     \
        RN0 = *(const int4*)(gs0 + ((SS) + 2) * 128);                         \
        RN1 = *(const int4*)(gs1 + ((SS) + 2) * 128);                         \
    }                                                                         \
    /* E2 operands for this step issued early (independent of LDS) */         \
    const int jg = jbase + (SS) * 128 + w * 32;                               \
    const float4 P0 = *(const float4*)(E2pg + jg + kg8);                      \
    const float4 P1 = *(const float4*)(E2pg + jg + kg8 + 4);                  \
    const float4 N0 = *(const float4*)(E2ng + jg + kg8);                      \
    const float4 N1 = *(const float4*)(E2ng + jg + kg8 + 4);                  \
    /* write stage SS+1 into the other buffer */                              \
    if ((SS) + 1 < NSS) {                                                     \
        *(int4*)(LWN)       = RW0;                                            \
        *(int4*)(LWN + 256) = RW1;                                            \
    }                                                                         \
    asm volatile("s_waitcnt lgkmcnt(0)" ::: "memory");                        \
    __builtin_amdgcn_s_barrier();                                             \
    __builtin_amdgcn_sched_barrier(0);                                        \
    const unsigned short* Ap = Asw + (size_t)(jg >> 5) * 512 + l * 8;         \
    const bf16x8 A0 = *(const bf16x8*)(Ap);                                   \
    const bf16x8 A1 = *(const bf16x8*)(Ap + 131072);                          \
    const bf16x8 A2 = *(const bf16x8*)(Ap + 262144);                          \
    const bf16x8 A3 = *(const bf16x8*)(Ap + 393216);                          \
    const int4 m0 = *(const int4*)&bufS[(SS) & 1][il * 128 + w * 32 + kg8];   \
    const int4 m1 = *(const int4*)&bufS[(SS) & 1][il * 128 + w * 32 + kg8 + 4];\
    const float p0 = SCM(P0.x, N0.x, m0.x);                                   \
    const float p1 = SCM(P0.y, N0.y, m0.y);                                   \
    const float p2 = SCM(P0.z, N0.z, m0.z);                                   \
    const float p3 = SCM(P0.w, N0.w, m0.w);                                   \
    const float p4 = SCM(P1.x, N1.x, m1.x);                                   \
    const float p5 = SCM(P1.y, N1.y, m1.y);                                   \
    const float p6 = SCM(P1.z, N1.z, m1.z);                                   \
    const float p7 = SCM(P1.w, N1.w, m1.w);                                   \
    rs += ((p0 + p1) + (p2 + p3)) + ((p4 + p5) + (p6 + p7));                  \
    uint4 wa;                                                                 \
    asm("v_cvt_pk_bf16_f32 %0, %1, %2" : "=v"(wa.x) : "v"(p0), "v"(p1));      \
    asm("v_cvt_pk_bf16_f32 %0, %1, %2" : "=v"(wa.y) : "v"(p2), "v"(p3));      \
    asm("v_cvt_pk_bf16_f32 %0, %1, %2" : "=v"(wa.z) : "v"(p4), "v"(p5));      \
    asm("v_cvt_pk_bf16_f32 %0, %1, %2" : "=v"(wa.w) : "v"(p6), "v"(p7));      \
    const bf16x8 BA = __builtin_bit_cast(bf16x8, wa);                         \
    a0 = __builtin_amdgcn_mfma_f32_16x16x32_bf16(A0, BA, a0, 0, 0, 0);        \
    a1 = __builtin_amdgcn_mfma_f32_16x16x32_bf16(A1, BA, a1, 0, 0, 0);        \
    a2 = __builtin_amdgcn_mfma_f32_16x16x32_bf16(A2, BA, a2, 0, 0, 0);        \
    a3 = __builtin_amdgcn_mfma_f32_16x16x32_bf16(A3, BA, a3, 0, 0, 0);        \
    __builtin_amdgcn_sched_barrier(0);                                        \
    __builtin_amdgcn_s_barrier();                                             \
} while (0)

    for (int sp = 0; sp < NSS; sp += 2) {
        STEP(sp,     rA0, rA1, rB0, rB1, lw1);  // even: gload->rA, write rB->buf1
        STEP(sp + 1, rB0, rB1, rA0, rA1, lw0);  // odd : gload->rB, write rA->buf0
    }
#undef STEP
#undef SCM

    // ---- epilogue: reduce the 4 waves' partials ----
    rs += __shfl_xor(rs, 16, 64);
    rs += __shfl_xor(rs, 32, 64);

    __syncthreads();                 // safe full drain, once; reuse bufS
    float*  red = (float*)bufS;      // [4 waves][64 lanes][4 q][4 r] = 16 KB
    float4* r4  = (float4*)red;
    r4[(w * 64 + l) * 4 + 0] = *(float4*)&a0;
    r4[(w * 64 + l) * 4 + 1] = *(float4*)&a1;
    r4[(w * 64 + l) * 4 + 2] = *(float4*)&a2;
    r4[(w * 64 + l) * 4 + 3] = *(float4*)&a3;
    if (l < 16) redl[w * 16 + il] = rs;
    __syncthreads();

    // writer: thread t -> row i = t>>4, col quad n0 = (t&15)*4 (coalesced)
    const int i  = tid >> 4;
    const int n0 = (tid & 15) * 4;
    float4 o;
    float* op = &o.x;
    #pragma unroll
    for (int e = 0; e < 4; ++e) {
        const int n   = n0 + e;
        const int q   = n >> 4;
        const int kgx = (n >> 2) & 3;
        const int r   = n & 3;
        float s = 0.f;
        #pragma unroll
        for (int wv = 0; wv < 4; ++wv)
            s += red[((wv * 64 + kgx * 16 + i) * 4 + q) * 4 + r];
        op[e] = s;
    }
    *(float4*)&Opart[((size_t)split * NN + i0 + i) * OUTF + n0] = o;
    if (tid < 16)
        lpart[(size_t)split * NN + i0 + tid] =
            (redl[tid] + redl[16 + tid]) + (redl[32 + tid] + redl[48 + tid]);
}

// ---------------------------------------------------------------------------
// Kernel 3: combine the 2 j-split partials and normalize.
// ---------------------------------------------------------------------------
__global__ __launch_bounds__(256) void k3_combine(
    const float* __restrict__ Opart, const float* __restrict__ lpart,
    float* __restrict__ out)
{
    const int f4 = blockIdx.x * 256 + threadIdx.x;   // 0..131071
    const int i  = f4 >> 4;
    float4 o0 = *(const float4*)&Opart[(size_t)f4 * 4];
    float4 o1 = *(const float4*)&Opart[(size_t)NN * OUTF + (size_t)f4 * 4];
    float inv = 1.0f / (lpart[i] + lpart[NN + i]);
    float4 r;
    r.x = (o0.x + o1.x) * inv;
    r.y = (o0.y + o1.y) * inv;
    r.z = (o0.z + o1.z) * inv;
    r.w = (o0.w + o1.w) * inv;
    *(float4*)&out[(size_t)f4 * 4] = r;
}

extern "C" void kernel_launch(void* const* d_in, const int* in_sizes, int n_in,
                              void* d_out, int out_size, void* d_ws, size_t ws_size,
                              hipStream_t stream) {
    const float* x   = (const float*)d_in[0];
    const int*   adj = (const int*)d_in[1];
    const float* W   = (const float*)d_in[2];
    const float* a   = (const float*)d_in[3];
    float* out = (float*)d_out;

    char* ws = (char*)d_ws;
    unsigned short* Asw = (unsigned short*)ws;                 // 1 MB
    float* U     = (float*)(ws + (1 << 20));                   // 32 KB
    float* E2p   = (float*)(ws + (1 << 20) + 32768);           // 32 KB
    float* E2n   = (float*)(ws + (1 << 20) + 65536);           // 32 KB
    float* lpart = (float*)(ws + (1 << 20) + 98304);           // 64 KB
    float* Opart = (float*)(ws + (1 << 20) + 98304 + 65536);   // 4 MB

    k1_gemm<<<512, 256, 0, stream>>>(x, W, a, Asw, U, E2p, E2n);
    k2_fused<<<1024, 256, 0, stream>>>(adj, Asw, U, E2p, E2n, Opart, lpart);
    k3_combine<<<512, 256, 0, stream>>>(Opart, lpart, out);
}

// Round 14
// 110.461 us; speedup vs baseline: 1.0112x; 1.0112x over previous
//
#include <hip/hip_runtime.h>
#include <cstdint>
#include <cstddef>

#define NN 8192
#define INF 512
#define OUTF 64
#define ALPHA 0.2f
#define NSPLIT 8
#define JSPLIT (NN / NSPLIT)   // 1024

typedef short bf16x8 __attribute__((ext_vector_type(8)));
typedef float f32x4 __attribute__((ext_vector_type(4)));

static __device__ inline unsigned short f2bf(float f) {
    unsigned u = __builtin_bit_cast(unsigned, f);
    unsigned r = (u + 0x7FFFu + ((u >> 16) & 1u)) >> 16;
    return (unsigned short)r;
}

// ---------------------------------------------------------------------------
// Kernel 1: Wh = x @ W (proven path). Writes Asw (MFMA-A-swizzled bf16 Wh),
// U = exp(0.8 s1), E2p = exp(s2), E2n = exp(0.2 s2).
// ---------------------------------------------------------------------------
__global__ __launch_bounds__(256) void k1_gemm(
    const float* __restrict__ x, const float* __restrict__ W,
    const float* __restrict__ a, unsigned short* __restrict__ Asw,
    float* __restrict__ U, float* __restrict__ E2p, float* __restrict__ E2n)
{
    const int tid = threadIdx.x;
    const int i0  = blockIdx.x * 16;
    const int w   = __builtin_amdgcn_readfirstlane(tid >> 6);
    const int c   = tid & 63;

    const float* xr = x + (size_t)(i0 + 4 * w) * INF;
    const float* Wc = W + c;
    float acc[4] = {0.f, 0.f, 0.f, 0.f};

    #pragma unroll 4
    for (int kk = 0; kk < 128; ++kk) {
        const float4 x0 = *(const float4*)(xr + 0 * INF + kk * 4);
        const float4 x1 = *(const float4*)(xr + 1 * INF + kk * 4);
        const float4 x2 = *(const float4*)(xr + 2 * INF + kk * 4);
        const float4 x3 = *(const float4*)(xr + 3 * INF + kk * 4);
        const float w0 = Wc[(kk * 4 + 0) * OUTF];
        const float w1 = Wc[(kk * 4 + 1) * OUTF];
        const float w2 = Wc[(kk * 4 + 2) * OUTF];
        const float w3 = Wc[(kk * 4 + 3) * OUTF];
        acc[0] = fmaf(x0.x, w0, fmaf(x0.y, w1, fmaf(x0.z, w2, fmaf(x0.w, w3, acc[0]))));
        acc[1] = fmaf(x1.x, w0, fmaf(x1.y, w1, fmaf(x1.z, w2, fmaf(x1.w, w3, acc[1]))));
        acc[2] = fmaf(x2.x, w0, fmaf(x2.y, w1, fmaf(x2.z, w2, fmaf(x2.w, w3, acc[2]))));
        acc[3] = fmaf(x3.x, w0, fmaf(x3.y, w1, fmaf(x3.z, w2, fmaf(x3.w, w3, acc[3]))));
    }

    const float a1c = a[c];
    const float a2c = a[64 + c];
    #pragma unroll
    for (int q = 0; q < 4; ++q) {
        float v1 = acc[q] * a1c;
        float v2 = acc[q] * a2c;
        #pragma unroll
        for (int m = 32; m; m >>= 1) {
            v1 += __shfl_xor(v1, m, 64);
            v2 += __shfl_xor(v2, m, 64);
        }
        if (c == 0) {
            const int i = i0 + 4 * w + q;
            U[i]   = __expf((1.0f - ALPHA) * v1);
            E2p[i] = __expf(v2);
            E2n[i] = __expf(ALPHA * v2);
        }
    }

    const int i   = i0 + 4 * w;
    const int jt  = i >> 5;
    const int sub = (i >> 3) & 3;
    const int e0  = i & 7;
    ushort4 pk;
    pk.x = f2bf(acc[0]); pk.y = f2bf(acc[1]);
    pk.z = f2bf(acc[2]); pk.w = f2bf(acc[3]);
    *(ushort4*)&Asw[((size_t)(c >> 4) * 256 + jt) * 512 + ((c & 15) + 16 * sub) * 8 + e0] = pk;
}

// ---------------------------------------------------------------------------
// Kernel 2 (fused, phase-separated): block = 32 rows x 1024-col split.
// Phase A: stream own 128 KB adj sub-block, coalesced 1KB/instr, 16 dwords/
// lane in flight; pack bits via __ballot into LDS words. ONE barrier.
// Phase B: proven k2 body (factored score, in-step A-loads, ping-pong),
// waves split the 32 j-steps stride-4; round-12-validated LDS reduce.
// Co-resident blocks desync -> compute hides under other blocks' streams.
// ---------------------------------------------------------------------------
__global__ __launch_bounds__(256, 4) void k2_fused(
    const int* __restrict__ adj, const unsigned short* __restrict__ Asw,
    const float* __restrict__ Ug, const float* __restrict__ E2pg,
    const float* __restrict__ E2ng,
    float* __restrict__ Opart, float* __restrict__ lpart)
{
    __shared__ char smem[33280];
    unsigned (*lm)[34] = (unsigned(*)[34])smem;   // mask words, 4.4 KB
    float* red  = (float*)smem;                   // 32 KB (overlay, post-B)
    float* redl = (float*)(smem + 32768);         // 512 B

    const int tid   = threadIdx.x;
    const int l     = tid & 63;
    const int w     = tid >> 6;
    const int split = blockIdx.x & (NSPLIT - 1);
    const int i0    = (int)(blockIdx.x >> 3) * 32;
    const int jbase = split * JSPLIT;
    const int jb32  = jbase >> 5;

    // ---------------- phase A: adj -> bit words in LDS ----------------
    // rep r (0..127): row = r>>2, col chunk = (r&3)*256 + tid (1KB coalesced)
    {
        const int* arow0 = adj + (size_t)i0 * NN + jbase;
        int vals[16];
        for (int batch = 0; batch < 8; ++batch) {
            #pragma unroll
            for (int u = 0; u < 16; ++u) {
                const int rep = batch * 16 + u;
                vals[u] = arow0[(size_t)(rep >> 2) * NN + (rep & 3) * 256 + tid];
            }
            #pragma unroll
            for (int u = 0; u < 16; ++u) {
                const int rep = batch * 16 + u;
                const unsigned long long b = __ballot(vals[u] != 0);
                if ((tid & 63) == 0) {
                    const int row = rep >> 2;
                    const int wi  = (rep & 3) * 8 + w * 2;
                    *(unsigned long long*)&lm[row][wi] = b;
                }
            }
        }
    }
    __syncthreads();

    // ---------------- phase B: wave w -> steps t = w, w+4, ..., w+28 ----
    const int il  = l & 15;
    const int kg  = l >> 4;
    const int kg8 = kg * 8;
    const float ua = Ug[i0 + il];
    const float ub = Ug[i0 + 16 + il];

    f32x4 a00 = {0,0,0,0}, a01 = {0,0,0,0}, a10 = {0,0,0,0}, a11 = {0,0,0,0};
    f32x4 a20 = {0,0,0,0}, a21 = {0,0,0,0}, a30 = {0,0,0,0}, a31 = {0,0,0,0};
    float rsA = 0.f, rsB = 0.f;

    int t = w;
    float4 pc0 = *(const float4*)(E2pg + jbase + t * 32 + kg8);
    float4 pc1 = *(const float4*)(E2pg + jbase + t * 32 + kg8 + 4);
    float4 nc0 = *(const float4*)(E2ng + jbase + t * 32 + kg8);
    float4 nc1 = *(const float4*)(E2ng + jbase + t * 32 + kg8 + 4);
    unsigned bAc = (lm[il][t]      >> kg8) & 0xffu;
    unsigned bBc = (lm[il + 16][t] >> kg8) & 0xffu;

#define SCM(UU, EP, EN, BITS, K)                                              \
    ((((BITS) >> (K)) & 1u) ? fmaxf((UU) * (EP), (EN)) : 0.f)

    #pragma unroll
    for (int s = 0; s < 8; ++s) {
        // A-fragments for THIS step (score math below covers their latency)
        const unsigned short* Ap = Asw + (size_t)(jb32 + t) * 512 + l * 8;
        const bf16x8 A0 = *(const bf16x8*)(Ap);
        const bf16x8 A1 = *(const bf16x8*)(Ap + 131072);
        const bf16x8 A2 = *(const bf16x8*)(Ap + 262144);
        const bf16x8 A3 = *(const bf16x8*)(Ap + 393216);

        // prefetch E2/mask for next step (stride 4)
        const int tn = (s < 7) ? t + 4 : t;
        float4 pn0 = *(const float4*)(E2pg + jbase + tn * 32 + kg8);
        float4 pn1 = *(const float4*)(E2pg + jbase + tn * 32 + kg8 + 4);
        float4 nn0 = *(const float4*)(E2ng + jbase + tn * 32 + kg8);
        float4 nn1 = *(const float4*)(E2ng + jbase + tn * 32 + kg8 + 4);
        unsigned bAn = (lm[il][tn]      >> kg8) & 0xffu;
        unsigned bBn = (lm[il + 16][tn] >> kg8) & 0xffu;

        // score math (5 VALU/score, no transcendentals)
        const float p0 = SCM(ua, pc0.x, nc0.x, bAc, 0);
        const float p1 = SCM(ua, pc0.y, nc0.y, bAc, 1);
        const float p2 = SCM(ua, pc0.z, nc0.z, bAc, 2);
        const float p3 = SCM(ua, pc0.w, nc0.w, bAc, 3);
        const float p4 = SCM(ua, pc1.x, nc1.x, bAc, 4);
        const float p5 = SCM(ua, pc1.y, nc1.y, bAc, 5);
        const float p6 = SCM(ua, pc1.z, nc1.z, bAc, 6);
        const float p7 = SCM(ua, pc1.w, nc1.w, bAc, 7);
        const float q0 = SCM(ub, pc0.x, nc0.x, bBc, 0);
        const float q1 = SCM(ub, pc0.y, nc0.y, bBc, 1);
        const float q2 = SCM(ub, pc0.z, nc0.z, bBc, 2);
        const float q3 = SCM(ub, pc0.w, nc0.w, bBc, 3);
        const float q4 = SCM(ub, pc1.x, nc1.x, bBc, 4);
        const float q5 = SCM(ub, pc1.y, nc1.y, bBc, 5);
        const float q6 = SCM(ub, pc1.z, nc1.z, bBc, 6);
        const float q7 = SCM(ub, pc1.w, nc1.w, bBc, 7);

        rsA += ((p0 + p1) + (p2 + p3)) + ((p4 + p5) + (p6 + p7));
        rsB += ((q0 + q1) + (q2 + q3)) + ((q4 + q5) + (q6 + q7));

        uint4 wa, wb;
        asm("v_cvt_pk_bf16_f32 %0, %1, %2" : "=v"(wa.x) : "v"(p0), "v"(p1));
        asm("v_cvt_pk_bf16_f32 %0, %1, %2" : "=v"(wa.y) : "v"(p2), "v"(p3));
        asm("v_cvt_pk_bf16_f32 %0, %1, %2" : "=v"(wa.z) : "v"(p4), "v"(p5));
        asm("v_cvt_pk_bf16_f32 %0, %1, %2" : "=v"(wa.w) : "v"(p6), "v"(p7));
        asm("v_cvt_pk_bf16_f32 %0, %1, %2" : "=v"(wb.x) : "v"(q0), "v"(q1));
        asm("v_cvt_pk_bf16_f32 %0, %1, %2" : "=v"(wb.y) : "v"(q2), "v"(q3));
        asm("v_cvt_pk_bf16_f32 %0, %1, %2" : "=v"(wb.z) : "v"(q4), "v"(q5));
        asm("v_cvt_pk_bf16_f32 %0, %1, %2" : "=v"(wb.w) : "v"(q6), "v"(q7));
        const bf16x8 BA = __builtin_bit_cast(bf16x8, wa);
        const bf16x8 BB = __builtin_bit_cast(bf16x8, wb);

        a00 = __builtin_amdgcn_mfma_f32_16x16x32_bf16(A0, BA, a00, 0, 0, 0);
        a01 = __builtin_amdgcn_mfma_f32_16x16x32_bf16(A0, BB, a01, 0, 0, 0);
        a10 = __builtin_amdgcn_mfma_f32_16x16x32_bf16(A1, BA, a10, 0, 0, 0);
        a11 = __builtin_amdgcn_mfma_f32_16x16x32_bf16(A1, BB, a11, 0, 0, 0);
        a20 = __builtin_amdgcn_mfma_f32_16x16x32_bf16(A2, BA, a20, 0, 0, 0);
        a21 = __builtin_amdgcn_mfma_f32_16x16x32_bf16(A2, BB, a21, 0, 0, 0);
        a30 = __builtin_amdgcn_mfma_f32_16x16x32_bf16(A3, BA, a30, 0, 0, 0);
        a31 = __builtin_amdgcn_mfma_f32_16x16x32_bf16(A3, BB, a31, 0, 0, 0);

        t = tn;
        pc0 = pn0; pc1 = pn1; nc0 = nn0; nc1 = nn1;
        bAc = bAn; bBc = bBn;
    }
#undef SCM

    // ---- epilogue: round-12-validated cross-wave reduce ----
    rsA += __shfl_xor(rsA, 16, 64);
    rsA += __shfl_xor(rsA, 32, 64);
    rsB += __shfl_xor(rsB, 16, 64);
    rsB += __shfl_xor(rsB, 32, 64);

    __syncthreads();                 // all waves done reading lm; overlay red
    float* rw = red + w * 2048 + l * 32;
    *(float4*)(rw + 0)  = *(float4*)&a00;
    *(float4*)(rw + 4)  = *(float4*)&a01;
    *(float4*)(rw + 8)  = *(float4*)&a10;
    *(float4*)(rw + 12) = *(float4*)&a11;
    *(float4*)(rw + 16) = *(float4*)&a20;
    *(float4*)(rw + 20) = *(float4*)&a21;
    *(float4*)(rw + 24) = *(float4*)&a30;
    *(float4*)(rw + 28) = *(float4*)&a31;
    if (l < 16) {
        redl[w * 32 + il]      = rsA;
        redl[w * 32 + 16 + il] = rsB;
    }
    __syncthreads();

    const int l2  = tid >> 2, q2 = tid & 3;
    const int il2 = l2 & 15, kg2 = l2 >> 4;
    #pragma unroll
    for (int h = 0; h < 2; ++h) {
        const int idx = l2 * 32 + q2 * 8 + h * 4;
        float4 s0 = *(float4*)(red + idx);
        float4 s1 = *(float4*)(red + 2048 + idx);
        float4 s2 = *(float4*)(red + 4096 + idx);
        float4 s3 = *(float4*)(red + 6144 + idx);
        float4 s;
        s.x = (s0.x + s1.x) + (s2.x + s3.x);
        s.y = (s0.y + s1.y) + (s2.y + s3.y);
        s.z = (s0.z + s1.z) + (s2.z + s3.z);
        s.w = (s0.w + s1.w) + (s2.w + s3.w);
        *(float4*)&Opart[((size_t)split * NN + i0 + h * 16 + il2) * OUTF
                         + q2 * 16 + kg2 * 4] = s;
    }
    if (tid < 32)
        lpart[(size_t)split * NN + i0 + tid] =
            (redl[tid] + redl[32 + tid]) + (redl[64 + tid] + redl[96 + tid]);
}

// ---------------------------------------------------------------------------
// Kernel 3: combine the 8 j-split partials and normalize.
// ---------------------------------------------------------------------------
__global__ __launch_bounds__(256) void k3_combine(
    const float* __restrict__ Opart, const float* __restrict__ lpart,
    float* __restrict__ out)
{
    const int f4 = blockIdx.x * 256 + threadIdx.x;
    const int i  = f4 >> 4;

    float4 r = {0.f, 0.f, 0.f, 0.f};
    float  lsum = 0.f;
    #pragma unroll
    for (int s = 0; s < NSPLIT; ++s) {
        float4 o = *(const float4*)&Opart[(size_t)s * NN * OUTF + (size_t)f4 * 4];
        r.x += o.x; r.y += o.y; r.z += o.z; r.w += o.w;
        lsum += lpart[(size_t)s * NN + i];
    }
    float inv = 1.0f / lsum;
    r.x *= inv; r.y *= inv; r.z *= inv; r.w *= inv;
    *(float4*)&out[(size_t)f4 * 4] = r;
}

extern "C" void kernel_launch(void* const* d_in, const int* in_sizes, int n_in,
                              void* d_out, int out_size, void* d_ws, size_t ws_size,
                              hipStream_t stream) {
    const float* x   = (const float*)d_in[0];
    const int*   adj = (const int*)d_in[1];
    const float* W   = (const float*)d_in[2];
    const float* a   = (const float*)d_in[3];
    float* out = (float*)d_out;

    char* ws = (char*)d_ws;
    unsigned short* Asw = (unsigned short*)ws;                 // 1 MB
    float* U     = (float*)(ws + (1 << 20));                   // 32 KB
    float* E2p   = (float*)(ws + (1 << 20) + 32768);           // 32 KB
    float* E2n   = (float*)(ws + (1 << 20) + 65536);           // 32 KB
    float* lpart = (float*)(ws + (1 << 20) + 98304);           // 256 KB
    float* Opart = (float*)(ws + (1 << 20) + 98304 + 262144);  // 16 MB

    k1_gemm<<<512, 256, 0, stream>>>(x, W, a, Asw, U, E2p, E2n);
    k2_fused<<<2048, 256, 0, stream>>>(adj, Asw, U, E2p, E2n, Opart, lpart);
    k3_combine<<<512, 256, 0, stream>>>(Opart, lpart, out);
}